// Round 1
// baseline (1023.917 us; speedup 1.0000x reference)
//
#include <hip/hip_runtime.h>
#include <cstdint>

#define CE_BATCH 4096
#define CE_VOCAB 50257

__global__ __launch_bounds__(256) void ce_kernel(const float* __restrict__ pred,
                                                 const int* __restrict__ y,
                                                 float* __restrict__ out) {
    const int b = blockIdx.x;
    const float* __restrict__ row = pred + (size_t)b * CE_VOCAB;
    const int tid = threadIdx.x;

    // Online logsumexp state
    float m = -INFINITY;
    float s = 0.0f;

    // Rows are only 4B-aligned relative to each other (50257 % 4 == 1).
    // Peel scalar prefix so float4 region is 16B aligned.
    int lead = (int)(((16u - ((uintptr_t)row & 15u)) & 15u) >> 2);
    if (lead > CE_VOCAB) lead = CE_VOCAB;
    if (tid < lead) {
        m = row[tid];
        s = 1.0f;
    }

    const int nvec = (CE_VOCAB - lead) >> 2;  // number of float4s
    const float4* __restrict__ vrow = (const float4*)(row + lead);
    for (int i = tid; i < nvec; i += 256) {
        float4 v = vrow[i];
        float m4 = fmaxf(fmaxf(v.x, v.y), fmaxf(v.z, v.w));
        float s4 = __expf(v.x - m4) + __expf(v.y - m4) +
                   __expf(v.z - m4) + __expf(v.w - m4);
        float nm = fmaxf(m, m4);
        s = s * __expf(m - nm) + s4 * __expf(m4 - nm);
        m = nm;
    }

    // Tail (0..3 elements)
    int t = lead + (nvec << 2) + tid;
    if (t < CE_VOCAB) {
        float x = row[t];
        float nm = fmaxf(m, x);
        s = s * __expf(m - nm) + __expf(x - nm);
        m = nm;
    }

    // Wave (64-lane) butterfly reduction of (m, s)
    #pragma unroll
    for (int off = 1; off < 64; off <<= 1) {
        float om = __shfl_xor(m, off, 64);
        float os = __shfl_xor(s, off, 64);
        float nm = fmaxf(m, om);
        s = s * __expf(m - nm) + os * __expf(om - nm);
        m = nm;
    }

    __shared__ float sm[4];
    __shared__ float ss[4];
    const int wave = tid >> 6;
    if ((tid & 63) == 0) {
        sm[wave] = m;
        ss[wave] = s;
    }
    __syncthreads();

    if (tid == 0) {
        m = sm[0];
        s = ss[0];
        #pragma unroll
        for (int w = 1; w < 4; ++w) {
            float om = sm[w], os = ss[w];
            float nm = fmaxf(m, om);
            s = s * __expf(m - nm) + os * __expf(om - nm);
            m = nm;
        }
        float lse = m + __logf(s);
        float loss = lse - row[y[b]];
        atomicAdd(out, loss * (1.0f / CE_BATCH));
    }
}

extern "C" void kernel_launch(void* const* d_in, const int* in_sizes, int n_in,
                              void* d_out, int out_size, void* d_ws, size_t ws_size,
                              hipStream_t stream) {
    const float* pred = (const float*)d_in[0];
    const int* y = (const int*)d_in[1];
    float* out = (float*)d_out;

    // d_out is poisoned to 0xAA before every launch; zero it on-stream
    // (graph-capture safe, same pattern the harness itself uses).
    hipMemsetAsync(out, 0, sizeof(float), stream);

    ce_kernel<<<CE_BATCH, 256, 0, stream>>>(pred, y, out);
}